// Round 4
// baseline (203.249 us; speedup 1.0000x reference)
//
#include <hip/hip_runtime.h>
#include <hip/hip_bf16.h>

#define B_ 4
#define S_ 512
#define E_ 512
#define U_ 256

// 2*log2(e): folded into w/b1 so the tanh arg feeds exp2 directly.
#define KC 2.885390081777927f

#if __has_builtin(__builtin_amdgcn_exp2f)
#define EXP2F(x) __builtin_amdgcn_exp2f(x)
#else
#define EXP2F(x) __exp2f(x)
#endif

#if __has_builtin(__builtin_amdgcn_rcpf)
#define RCPF(x) __builtin_amdgcn_rcpf(x)
#else
#define RCPF(x) (1.0f / (x))
#endif

// ===========================================================================
// Shared fp32 GEMM core: 128(M) x 64(N) tile, 256 threads, 8x4 micro-tile,
// K-step 32, next-tile register prefetch.
//  - As[32][132]: [k][m], stride 132 -> per-wave A-frag reads & transposed
//    stores are <=2-way (free). 2x b128 frag reads / kk.
//  - Bs[32][68]:  [k][n], stride 68 -> staging stores 8 words/bank (ideal),
//    frag reads 2-way. 1x b128 frag read / kk.
//  - 32 FMA per 3 b128 reads -> VALU-bound (per-CU LDS pipe no longer binds).
// ===========================================================================
#define GEMM_CORE(APTR, BPTR, ALD, BLD, BSCALE)                                \
    __shared__ float As[32][132];                                              \
    __shared__ float Bs[32][68];                                               \
    const int tid = threadIdx.x;                                               \
    const int tm = tid >> 4;   /* 16 m-groups of 8 rows */                     \
    const int tn = tid & 15;   /* 16 n-groups of 4 cols */                     \
    const int ar = tid >> 1;                                                   \
    const int ak = (tid & 1) * 16;                                             \
    const int bk = tid >> 3;   /* block-level 0..31 */                         \
    const int bn = (tid & 7) * 8;                                              \
    float acc[8][4];                                                           \
    _Pragma("unroll") for (int i = 0; i < 8; ++i)                              \
        _Pragma("unroll") for (int q = 0; q < 4; ++q) acc[i][q] = 0.f;         \
    float4 sa[4]; float4 sb[2];                                                \
    _Pragma("unroll") for (int i = 0; i < 4; ++i)                              \
        sa[i] = *(const float4*)&APTR[(size_t)(m0 + ar) * ALD + ak + 4 * i];   \
    sb[0] = *(const float4*)&BPTR[(size_t)bk * BLD + n0 + bn];                 \
    sb[1] = *(const float4*)&BPTR[(size_t)bk * BLD + n0 + bn + 4];             \
    for (int k0 = 0; k0 < KDIM; k0 += 32) {                                    \
        __syncthreads();                                                       \
        _Pragma("unroll") for (int i = 0; i < 4; ++i) {                        \
            As[ak + 4 * i + 0][ar] = sa[i].x;                                  \
            As[ak + 4 * i + 1][ar] = sa[i].y;                                  \
            As[ak + 4 * i + 2][ar] = sa[i].z;                                  \
            As[ak + 4 * i + 3][ar] = sa[i].w;                                  \
        }                                                                      \
        *(float4*)&Bs[bk][bn] = make_float4(sb[0].x * BSCALE, sb[0].y * BSCALE,\
                                            sb[0].z * BSCALE, sb[0].w * BSCALE);\
        *(float4*)&Bs[bk][bn + 4] = make_float4(sb[1].x * BSCALE, sb[1].y * BSCALE,\
                                                sb[1].z * BSCALE, sb[1].w * BSCALE);\
        __syncthreads();                                                       \
        const int kn = (k0 + 32 < KDIM) ? (k0 + 32) : k0;                      \
        _Pragma("unroll") for (int i = 0; i < 4; ++i)                          \
            sa[i] = *(const float4*)&APTR[(size_t)(m0 + ar) * ALD + kn + ak + 4 * i];\
        sb[0] = *(const float4*)&BPTR[(size_t)(kn + bk) * BLD + n0 + bn];      \
        sb[1] = *(const float4*)&BPTR[(size_t)(kn + bk) * BLD + n0 + bn + 4];  \
        _Pragma("unroll") for (int kk = 0; kk < 32; ++kk) {                    \
            const float4 alo = *(const float4*)&As[kk][tm * 8];                \
            const float4 ahi = *(const float4*)&As[kk][tm * 8 + 4];            \
            const float4 b4 = *(const float4*)&Bs[kk][tn * 4];                 \
            acc[0][0] = fmaf(alo.x, b4.x, acc[0][0]); acc[0][1] = fmaf(alo.x, b4.y, acc[0][1]);\
            acc[0][2] = fmaf(alo.x, b4.z, acc[0][2]); acc[0][3] = fmaf(alo.x, b4.w, acc[0][3]);\
            acc[1][0] = fmaf(alo.y, b4.x, acc[1][0]); acc[1][1] = fmaf(alo.y, b4.y, acc[1][1]);\
            acc[1][2] = fmaf(alo.y, b4.z, acc[1][2]); acc[1][3] = fmaf(alo.y, b4.w, acc[1][3]);\
            acc[2][0] = fmaf(alo.z, b4.x, acc[2][0]); acc[2][1] = fmaf(alo.z, b4.y, acc[2][1]);\
            acc[2][2] = fmaf(alo.z, b4.z, acc[2][2]); acc[2][3] = fmaf(alo.z, b4.w, acc[2][3]);\
            acc[3][0] = fmaf(alo.w, b4.x, acc[3][0]); acc[3][1] = fmaf(alo.w, b4.y, acc[3][1]);\
            acc[3][2] = fmaf(alo.w, b4.z, acc[3][2]); acc[3][3] = fmaf(alo.w, b4.w, acc[3][3]);\
            acc[4][0] = fmaf(ahi.x, b4.x, acc[4][0]); acc[4][1] = fmaf(ahi.x, b4.y, acc[4][1]);\
            acc[4][2] = fmaf(ahi.x, b4.z, acc[4][2]); acc[4][3] = fmaf(ahi.x, b4.w, acc[4][3]);\
            acc[5][0] = fmaf(ahi.y, b4.x, acc[5][0]); acc[5][1] = fmaf(ahi.y, b4.y, acc[5][1]);\
            acc[5][2] = fmaf(ahi.y, b4.z, acc[5][2]); acc[5][3] = fmaf(ahi.y, b4.w, acc[5][3]);\
            acc[6][0] = fmaf(ahi.z, b4.x, acc[6][0]); acc[6][1] = fmaf(ahi.z, b4.y, acc[6][1]);\
            acc[6][2] = fmaf(ahi.z, b4.z, acc[6][2]); acc[6][3] = fmaf(ahi.z, b4.w, acc[6][3]);\
            acc[7][0] = fmaf(ahi.w, b4.x, acc[7][0]); acc[7][1] = fmaf(ahi.w, b4.y, acc[7][1]);\
            acc[7][2] = fmaf(ahi.w, b4.z, acc[7][2]); acc[7][3] = fmaf(ahi.w, b4.w, acc[7][3]);\
        }                                                                      \
    }

// ---------------------------------------------------------------------------
// Kernel 1: pre-projections. grid (16, 4, 2) = 128 blocks.
//   z==0: keySt[b][u][j] = KC * (h1[b,j,:] @ w1[:,u])        (transposed)
//   z==1: qryS [b][i][u] = KC * (h2[b,i,:] @ w2[:,u] + b1[u])
// ---------------------------------------------------------------------------
#define KDIM E_
__global__ __launch_bounds__(256) void gemm_pre(
    const float* __restrict__ h1, const float* __restrict__ h2,
    const float* __restrict__ w, const float* __restrict__ b1,
    float* __restrict__ keySt, float* __restrict__ qryS)
{
    const int z = blockIdx.z;
    const float* __restrict__ A = z ? h2 : h1;
    const float* __restrict__ Bw = w + (z ? (E_ * U_) : 0);
    const int m0 = blockIdx.x * 128;      // global row (b*S + s)
    const int n0 = blockIdx.y * 64;       // u

    GEMM_CORE(A, Bw, E_, U_, KC)

    if (z == 0) {
        const int bb = m0 >> 9;
        const int j0 = (m0 & (S_ - 1)) + tm * 8;
#pragma unroll
        for (int c = 0; c < 4; ++c) {
            float* dst = &keySt[((size_t)bb * U_ + n0 + tn * 4 + c) * S_ + j0];
            *(float4*)dst = make_float4(acc[0][c], acc[1][c], acc[2][c], acc[3][c]);
            *(float4*)(dst + 4) = make_float4(acc[4][c], acc[5][c], acc[6][c], acc[7][c]);
        }
    } else {
        float4 bq = *(const float4*)&b1[n0 + tn * 4];
        bq.x *= KC; bq.y *= KC; bq.z *= KC; bq.w *= KC;
#pragma unroll
        for (int r = 0; r < 8; ++r) {
            const int row = m0 + tm * 8 + r;
            *(float4*)&qryS[(size_t)row * U_ + n0 + tn * 4] =
                make_float4(acc[r][0] + bq.x, acc[r][1] + bq.y,
                            acc[r][2] + bq.z, acc[r][3] + bq.w);
        }
    }
}
#undef KDIM

// ---------------------------------------------------------------------------
// Kernel 2: scores + softmax -> normalized P. grid (256, 4) = 1024 blocks,
// 4 blocks/CU, 16 waves/CU. Thread t: j = 2t, 2t+1 for 2 query rows.
// q-rows / v are wave-uniform -> uniform loads (SMEM) used directly as SGPR
// operands; NO LDS in the inner loop.
// Identity: sum_u v_u*tanh(x_u) = const - 2*sum_u v_u/(exp(2x_u)+1); const,
// b2 and the -2 factor are handled via the softmax shift: with a = sum v*r,
// p = exp2((min(a) - a) * KC).
// ---------------------------------------------------------------------------
__global__ __launch_bounds__(256) void scores_kernel(
    const float* __restrict__ keySt, const float* __restrict__ qryS,
    const float* __restrict__ v, float* __restrict__ P)
{
    const int i0 = blockIdx.x * 2;
    const int b = blockIdx.y;
    const int t = threadIdx.x;

    __shared__ float smx[4][2], ssm[4][2];

    const float* __restrict__ q0p = qryS + ((size_t)b * S_ + i0) * U_;
    const float* __restrict__ q1p = q0p + U_;
    const float2* __restrict__ kb2 =
        (const float2*)(keySt + (size_t)b * U_ * S_) + t;

    float a00 = 0.f, a01 = 0.f, a10 = 0.f, a11 = 0.f;
#pragma unroll 8
    for (int u = 0; u < U_; ++u) {
        const float2 k2 = kb2[(size_t)u * (S_ / 2)];
        const float q0 = q0p[u];         // uniform -> SGPR
        const float q1 = q1p[u];         // uniform -> SGPR
        const float vu = v[u];           // uniform -> SGPR
        const float r00 = RCPF(EXP2F(q0 + k2.x) + 1.f);
        const float r01 = RCPF(EXP2F(q0 + k2.y) + 1.f);
        const float r10 = RCPF(EXP2F(q1 + k2.x) + 1.f);
        const float r11 = RCPF(EXP2F(q1 + k2.y) + 1.f);
        a00 = fmaf(vu, r00, a00); a01 = fmaf(vu, r01, a01);
        a10 = fmaf(vu, r10, a10); a11 = fmaf(vu, r11, a11);
    }

    // softmax over j: score = const - 2a -> p ~ exp2((mn - a)*KC), mn = min a
    float m0 = fminf(a00, a01), m1 = fminf(a10, a11);
#pragma unroll
    for (int off = 1; off < 64; off <<= 1) {
        m0 = fminf(m0, __shfl_xor(m0, off, 64));
        m1 = fminf(m1, __shfl_xor(m1, off, 64));
    }
    const int wv = t >> 6;
    if ((t & 63) == 0) { smx[wv][0] = m0; smx[wv][1] = m1; }
    __syncthreads();
    m0 = fminf(fminf(smx[0][0], smx[1][0]), fminf(smx[2][0], smx[3][0]));
    m1 = fminf(fminf(smx[0][1], smx[1][1]), fminf(smx[2][1], smx[3][1]));

    const float p00 = EXP2F((m0 - a00) * KC), p01 = EXP2F((m0 - a01) * KC);
    const float p10 = EXP2F((m1 - a10) * KC), p11 = EXP2F((m1 - a11) * KC);
    float s0 = p00 + p01, s1 = p10 + p11;
#pragma unroll
    for (int off = 1; off < 64; off <<= 1) {
        s0 += __shfl_xor(s0, off, 64);
        s1 += __shfl_xor(s1, off, 64);
    }
    if ((t & 63) == 0) { ssm[wv][0] = s0; ssm[wv][1] = s1; }
    __syncthreads();
    s0 = (ssm[0][0] + ssm[1][0]) + (ssm[2][0] + ssm[3][0]);
    s1 = (ssm[0][1] + ssm[1][1]) + (ssm[2][1] + ssm[3][1]);
    const float r0 = RCPF(s0), r1 = RCPF(s1);

    float* __restrict__ prow = P + ((size_t)b * S_ + i0) * S_ + 2 * t;
    *(float2*)prow = make_float2(p00 * r0, p01 * r0);
    *(float2*)(prow + S_) = make_float2(p10 * r1, p11 * r1);
}

// ---------------------------------------------------------------------------
// Kernel 3: out[b] = P[b] @ h1[b]. grid (4, 8, 4) = 128 blocks.
// ---------------------------------------------------------------------------
#define KDIM S_
__global__ __launch_bounds__(256) void pv_gemm(
    const float* __restrict__ P, const float* __restrict__ h1,
    float* __restrict__ out)
{
    const int b = blockIdx.z;
    const float* __restrict__ A = P + (size_t)b * S_ * S_;
    const float* __restrict__ Bh = h1 + (size_t)b * S_ * E_;
    const int m0 = blockIdx.x * 128;      // i
    const int n0 = blockIdx.y * 64;       // e

    GEMM_CORE(A, Bh, S_, E_, 1.0f)

#pragma unroll
    for (int r = 0; r < 8; ++r) {
        const int row = m0 + tm * 8 + r;
        *(float4*)&out[((size_t)b * S_ + row) * E_ + n0 + tn * 4] =
            make_float4(acc[r][0], acc[r][1], acc[r][2], acc[r][3]);
    }
}
#undef KDIM

extern "C" void kernel_launch(void* const* d_in, const int* in_sizes, int n_in,
                              void* d_out, int out_size, void* d_ws, size_t ws_size,
                              hipStream_t stream) {
    const float* h1 = (const float*)d_in[0];
    const float* h2 = (const float*)d_in[1];
    const float* w  = (const float*)d_in[2];
    const float* b1 = (const float*)d_in[3];
    const float* v  = (const float*)d_in[4];
    // d_in[5] = b2: cancels in softmax, unused.
    float* out = (float*)d_out;

    float* keySt = (float*)d_ws;                           // 2 MB
    float* qryS  = keySt + (size_t)B_ * U_ * S_;           // 2 MB
    float* P     = qryS + (size_t)B_ * S_ * U_;            // 4 MB

    dim3 g1(B_ * S_ / 128, U_ / 64, 2);
    gemm_pre<<<g1, dim3(256), 0, stream>>>(h1, h2, w, b1, keySt, qryS);

    dim3 g2(S_ / 2, B_);
    scores_kernel<<<g2, dim3(256), 0, stream>>>(keySt, qryS, v, P);

    dim3 g3(S_ / 128, E_ / 64, B_);
    pv_gemm<<<g3, dim3(256), 0, stream>>>(P, h1, out);
}

// Round 5
// 150.770 us; speedup vs baseline: 1.3481x; 1.3481x over previous
//
#include <hip/hip_runtime.h>
#include <hip/hip_bf16.h>

#define B_ 4
#define S_ 512
#define E_ 512
#define U_ 256

// 2*log2(e): folded into keySt/qryS so the tanh arg feeds exp2 directly.
#define KC 2.885390081777927f

#if __has_builtin(__builtin_amdgcn_exp2f)
#define EXP2F(x) __builtin_amdgcn_exp2f(x)
#else
#define EXP2F(x) __exp2f(x)
#endif
#if __has_builtin(__builtin_amdgcn_rcpf)
#define RCPF(x) __builtin_amdgcn_rcpf(x)
#else
#define RCPF(x) (1.0f / (x))
#endif

typedef __attribute__((ext_vector_type(8))) short bf16x8;
typedef __attribute__((ext_vector_type(4))) float f32x4;

__device__ __forceinline__ unsigned short bf16rn(float x) {
    unsigned int u = __float_as_uint(x);
    u = (u + 0x7FFFu + ((u >> 16) & 1u)) >> 16;   // RNE
    return (unsigned short)u;
}
__device__ __forceinline__ float bf16tof(unsigned short h) {
    return __uint_as_float(((unsigned int)h) << 16);
}

// ---------------------------------------------------------------------------
// Kernel 1: pre-projections via MFMA 16x16x32 bf16 with hi/lo split
// (3 MFMAs per chunk => ~fp32 accuracy; needed since output feeds tanh).
//   z==0: keySt[b][u][j] = KC * (h1[b,j,:] @ w1[:,u])        (j-contig)
//   z==1: qryS [b][i][u] = KC * (h2[b,i,:] @ w2[:,u] + b1[u])
// Block: 256 thr = 4 waves; tile 64(M) x 64(N); wave = 16m x 64n (4 accs).
// grid (32, 4, 2) = 256 blocks. W-chunks staged in LDS in B-frag order.
// ---------------------------------------------------------------------------
__global__ __launch_bounds__(256) void gemm_pre(
    const float* __restrict__ h1, const float* __restrict__ h2,
    const float* __restrict__ w, const float* __restrict__ b1,
    float* __restrict__ keySt, float* __restrict__ qryS)
{
    const int z = blockIdx.z;
    const float* __restrict__ A = z ? h2 : h1;
    const float* __restrict__ Bw = w + (z ? (E_ * U_) : 0);
    const int n0 = blockIdx.y * 64;
    const int tid = threadIdx.x;
    const int wv = tid >> 6, lane = tid & 63;
    const int quad = lane >> 4, l16 = lane & 15;
    const int m0w = blockIdx.x * 64 + wv * 16;     // this wave's 16 rows

    __shared__ bf16x8 Bh[4][64];   // B-frag order: [nsub][lane] -> 8 bf16 (hi)
    __shared__ bf16x8 Bl[4][64];   // (lo)

    // staging ids: thread t fills slot (nsub = t>>6, slane = t&63)
    const int sn = tid >> 6;
    const int sl = tid & 63;
    const int scol = n0 + sn * 16 + (sl & 15);
    const int skb = (sl >> 4) * 8;

    f32x4 acc[4];
#pragma unroll
    for (int i = 0; i < 4; ++i) acc[i] = (f32x4){0.f, 0.f, 0.f, 0.f};

    const float* __restrict__ Arow = A + (size_t)(m0w + l16) * E_;

    for (int kc = 0; kc < 16; ++kc) {
        // ---- A fragment: 8 k-consecutive fp32 of this lane's row ----
        const int kb = kc * 32 + quad * 8;
        const float4 x0 = *(const float4*)&Arow[kb];
        const float4 x1 = *(const float4*)&Arow[kb + 4];
        const float xs[8] = {x0.x, x0.y, x0.z, x0.w, x1.x, x1.y, x1.z, x1.w};
        bf16x8 ah, al;
#pragma unroll
        for (int j = 0; j < 8; ++j) {
            const unsigned short h = bf16rn(xs[j]);
            ah[j] = (short)h;
            al[j] = (short)bf16rn(xs[j] - bf16tof(h));
        }
        // ---- W chunk -> frag-order LDS (scaled by KC, split hi/lo) ----
        float wsv[8];
#pragma unroll
        for (int j = 0; j < 8; ++j)
            wsv[j] = Bw[(size_t)(kc * 32 + skb + j) * U_ + scol] * KC;
        bf16x8 wh, wl;
#pragma unroll
        for (int j = 0; j < 8; ++j) {
            const unsigned short h = bf16rn(wsv[j]);
            wh[j] = (short)h;
            wl[j] = (short)bf16rn(wsv[j] - bf16tof(h));
        }
        __syncthreads();
        Bh[sn][sl] = wh;
        Bl[sn][sl] = wl;
        __syncthreads();
#pragma unroll
        for (int ns = 0; ns < 4; ++ns) {
            const bf16x8 bh = Bh[ns][lane];
            const bf16x8 bl = Bl[ns][lane];
            acc[ns] = __builtin_amdgcn_mfma_f32_16x16x32_bf16(ah, bh, acc[ns], 0, 0, 0);
            acc[ns] = __builtin_amdgcn_mfma_f32_16x16x32_bf16(ah, bl, acc[ns], 0, 0, 0);
            acc[ns] = __builtin_amdgcn_mfma_f32_16x16x32_bf16(al, bh, acc[ns], 0, 0, 0);
        }
    }

    // C/D: row(M) = quad*4 + r, col(N) = l16
    if (z == 0) {
        const int bb = m0w >> 9;
        const int jloc = (m0w & (S_ - 1)) + quad * 4;
#pragma unroll
        for (int ns = 0; ns < 4; ++ns) {
            const int u = n0 + ns * 16 + l16;
            *(float4*)&keySt[((size_t)bb * U_ + u) * S_ + jloc] =
                make_float4(acc[ns][0], acc[ns][1], acc[ns][2], acc[ns][3]);
        }
    } else {
        const int row = m0w + quad * 4;
#pragma unroll
        for (int ns = 0; ns < 4; ++ns) {
            const int u = n0 + ns * 16 + l16;
            const float bias = KC * b1[u];
#pragma unroll
            for (int r = 0; r < 4; ++r)
                qryS[(size_t)(row + r) * U_ + u] = acc[ns][r] + bias;
        }
    }
}

// ---------------------------------------------------------------------------
// Kernel 2: scores + softmax -> P packed in MFMA A-frag order (bf16).
// 512 thr/block, thread t = column j, 2 query rows/block.
// grid (256, 4) = 1024 blocks x 8 waves = 32 waves/CU (max occupancy).
// Identity: sum_u v*tanh(x) = c - 2*sum_u v/(exp(2x)+1); c, b2 cancel.
// With a = sum v*r:  p ~ exp2((min(a) - a) * KC).
// Pack layout (per b): slot = ((i>>4)*16 + (j>>5))*64 + ((i&15) | (((j>>3)&3)<<4));
// element (j&7) inside the 8-bf16 slot.
// ---------------------------------------------------------------------------
__global__ __launch_bounds__(512) void scores_kernel(
    const float* __restrict__ keySt, const float* __restrict__ qryS,
    const float* __restrict__ v, unsigned short* __restrict__ Pp)
{
    const int i0 = blockIdx.x * 2;
    const int b = blockIdx.y;
    const int t = threadIdx.x;      // j = t

    __shared__ float smx[8][2], ssm[8][2];

    const float* __restrict__ q0p = qryS + ((size_t)b * S_ + i0) * U_;
    const float* __restrict__ q1p = q0p + U_;
    const float* __restrict__ kb = keySt + (size_t)b * U_ * S_ + t;

    float a0 = 0.f, a1 = 0.f;
#pragma unroll 8
    for (int u = 0; u < U_; ++u) {
        const float kv = kb[(size_t)u * S_];
        const float q0 = q0p[u];     // wave-uniform -> SGPR
        const float q1 = q1p[u];
        const float vu = v[u];
        a0 = fmaf(vu, RCPF(EXP2F(q0 + kv) + 1.f), a0);
        a1 = fmaf(vu, RCPF(EXP2F(q1 + kv) + 1.f), a1);
    }

    float m0 = a0, m1 = a1;
#pragma unroll
    for (int off = 1; off < 64; off <<= 1) {
        m0 = fminf(m0, __shfl_xor(m0, off, 64));
        m1 = fminf(m1, __shfl_xor(m1, off, 64));
    }
    const int wvi = t >> 6;
    if ((t & 63) == 0) { smx[wvi][0] = m0; smx[wvi][1] = m1; }
    __syncthreads();
    m0 = smx[0][0]; m1 = smx[0][1];
#pragma unroll
    for (int k = 1; k < 8; ++k) {
        m0 = fminf(m0, smx[k][0]);
        m1 = fminf(m1, smx[k][1]);
    }

    const float p0 = EXP2F((m0 - a0) * KC);
    const float p1 = EXP2F((m1 - a1) * KC);
    float s0 = p0, s1 = p1;
#pragma unroll
    for (int off = 1; off < 64; off <<= 1) {
        s0 += __shfl_xor(s0, off, 64);
        s1 += __shfl_xor(s1, off, 64);
    }
    if ((t & 63) == 0) { ssm[wvi][0] = s0; ssm[wvi][1] = s1; }
    __syncthreads();
    s0 = ssm[0][0]; s1 = ssm[0][1];
#pragma unroll
    for (int k = 1; k < 8; ++k) { s0 += ssm[k][0]; s1 += ssm[k][1]; }
    const float r0 = RCPF(s0), r1 = RCPF(s1);

    unsigned short* __restrict__ pb = Pp + (size_t)b * S_ * S_;
    const int kc = t >> 5;
    const int lp = ((t >> 3) & 3) << 4;
    const int jo = t & 7;
    const int itile = i0 >> 4;
    pb[(((itile * 16 + kc) * 64 + ((i0 & 15) | lp)) << 3) + jo] = bf16rn(p0 * r0);
    pb[(((itile * 16 + kc) * 64 + (((i0 + 1) & 15) | lp)) << 3) + jo] = bf16rn(p1 * r1);
}

// ---------------------------------------------------------------------------
// Kernel 3: out[b] = P[b] @ h1[b] via plain-bf16 MFMA (error ~0.004*||p||_2
// ~ 6e-4, within budget). A-frags come pre-packed from scores_kernel; h1
// chunks staged in LDS in B-frag order (converted on the fly).
// Block: 256 thr, tile 64i x 64e; grid (8, 8, 4) = 256 blocks.
// ---------------------------------------------------------------------------
__global__ __launch_bounds__(256) void pv_gemm(
    const unsigned short* __restrict__ Pp, const float* __restrict__ h1,
    float* __restrict__ out)
{
    const int b = blockIdx.z;
    const int e0 = blockIdx.y * 64;
    const int tid = threadIdx.x;
    const int wv = tid >> 6, lane = tid & 63;
    const int quad = lane >> 4, l16 = lane & 15;
    const int itile = blockIdx.x * 4 + wv;

    __shared__ bf16x8 Bs[4][64];

    const int sn = tid >> 6;
    const int sl = tid & 63;
    const int scol = e0 + sn * 16 + (sl & 15);
    const int skb = (sl >> 4) * 8;

    const float* __restrict__ hb = h1 + (size_t)b * S_ * E_;
    const bf16x8* __restrict__ Ab =
        (const bf16x8*)(Pp + (size_t)b * S_ * S_) + (size_t)itile * 16 * 64 + lane;

    f32x4 acc[4];
#pragma unroll
    for (int i = 0; i < 4; ++i) acc[i] = (f32x4){0.f, 0.f, 0.f, 0.f};

    for (int kc = 0; kc < 16; ++kc) {
        const bf16x8 a8 = Ab[kc * 64];
        bf16x8 bh;
#pragma unroll
        for (int j = 0; j < 8; ++j)
            bh[j] = (short)bf16rn(hb[(size_t)(kc * 32 + skb + j) * E_ + scol]);
        __syncthreads();
        Bs[sn][sl] = bh;
        __syncthreads();
#pragma unroll
        for (int ns = 0; ns < 4; ++ns)
            acc[ns] = __builtin_amdgcn_mfma_f32_16x16x32_bf16(a8, Bs[ns][lane], acc[ns], 0, 0, 0);
    }

    const int ig = itile * 16 + quad * 4;
#pragma unroll
    for (int ns = 0; ns < 4; ++ns) {
        const int eg = e0 + ns * 16 + l16;
#pragma unroll
        for (int r = 0; r < 4; ++r)
            out[((size_t)b * S_ + ig + r) * E_ + eg] = acc[ns][r];
    }
}

extern "C" void kernel_launch(void* const* d_in, const int* in_sizes, int n_in,
                              void* d_out, int out_size, void* d_ws, size_t ws_size,
                              hipStream_t stream) {
    const float* h1 = (const float*)d_in[0];
    const float* h2 = (const float*)d_in[1];
    const float* w  = (const float*)d_in[2];
    const float* b1 = (const float*)d_in[3];
    const float* v  = (const float*)d_in[4];
    // d_in[5] = b2: cancels in softmax, unused.
    float* out = (float*)d_out;

    float* keySt = (float*)d_ws;                            // 2 MB fp32
    float* qryS  = keySt + (size_t)B_ * U_ * S_;            // 2 MB fp32
    unsigned short* Pp = (unsigned short*)(qryS + (size_t)B_ * S_ * U_);  // 2 MB bf16

    dim3 g1(B_ * S_ / 64, U_ / 64, 2);
    gemm_pre<<<g1, dim3(256), 0, stream>>>(h1, h2, w, b1, keySt, qryS);

    dim3 g2(S_ / 2, B_);
    scores_kernel<<<g2, dim3(512), 0, stream>>>(keySt, qryS, v, Pp);

    dim3 g3(S_ / 64, E_ / 64, B_);
    pv_gemm<<<g3, dim3(256), 0, stream>>>(Pp, h1, out);
}